// Round 2
// baseline (175.870 us; speedup 1.0000x reference)
//
#include <hip/hip_runtime.h>

// TanhAttention: B=4, L=512, D=256
//   scores[b,i,j] = sum_d tanh(H[b,i,d]+H[b,j,d]) * w[d] + bias
//   alpha = softmax_j(scores); r = alpha @ H
// Outputs concatenated: r (524288 floats) then alpha (1048576 floats).
//
// Trick 1: sum_d w*tanh = (sum_d w) - 2*sum_d w * sigmoid, sigmoid = 1/(1+exp2(K*(hi+hj))),
//          K = 2*log2(e) pre-multiplied into the LDS copy of H.
// Trick 2: softmax shift-invariance cancels the row constant (sum w + bias) -> bias unused.
//
// R1 change vs R0: TI 8->4, grid 256->512 (2 blocks/CU = 16 waves/CU, was 8).
// Rationale: VALUBusy 48% @ Occupancy 21% -> latency-bound; two independent
// blocks/CU overlap each other's barriers/staging. LDS 44KB/block (<64KB WG cap,
// 2 fit in 160KB/CU). dd-loop unrolled x8 so consecutive-dd ds_reads merge to b64/b128.

#define B_ 4
#define L_ 512
#define D_ 256
#define TI 4            // i-rows per block
#define DT 16           // d-tile staged in LDS
#define PSTR 17         // padded LDS row stride (odd -> 2 lanes/bank = free)
#define NTHREADS 512

__global__ __launch_bounds__(NTHREADS, 4) void tanh_attn_kernel(
    const float* __restrict__ H, const float* __restrict__ w,
    float* __restrict__ rOut, float* __restrict__ aOut)
{
    __shared__ float hjs[L_ * PSTR];   // 512*17*4 = 34816 B (K-scaled H[b] d-tile)
    __shared__ float sc[TI * L_];      // 8192 B (scores, then alpha)
    __shared__ float ws[D_];           // 1024 B
    // total 44032 B -> 2 blocks/CU

    const int tid = threadIdx.x;
    const int blk = blockIdx.x;        // 0..511
    const int b   = blk >> 7;          // blk / (L_/TI)
    const int i0  = (blk & 127) * TI;

    const float K = 2.8853900817779268f;  // 2*log2(e)

    if (tid < D_) ws[tid] = w[tid];

    const int ti = tid >> 8;           // 0..1, wave-uniform; i = i0 + ti + 2*ii
    const int tj = tid & 255;          // 0..255, lane-consecutive; j = tj + 256*jj

    float acc[2][2];
    acc[0][0] = acc[0][1] = acc[1][0] = acc[1][1] = 0.0f;

    const float* Hb = H + (size_t)b * L_ * D_;

    for (int dt = 0; dt < D_ / DT; ++dt) {
        const int d0 = dt * DT;
        __syncthreads();   // previous tile's readers done (also covers ws on dt=0)
        // Stage 512 rows x DT cols, scaled by K: 2048 float4 / 512 threads = 4 each.
        #pragma unroll
        for (int rr = 0; rr < 4; ++rr) {
            int idx = rr * NTHREADS + tid;   // 0..2047
            int j   = idx >> 2;              // 4 float4 per row-tile
            int q   = idx & 3;
            const float4 hv = *(const float4*)(Hb + j * D_ + d0 + q * 4);
            float* dst = &hjs[j * PSTR + q * 4];
            dst[0] = hv.x * K; dst[1] = hv.y * K; dst[2] = hv.z * K; dst[3] = hv.w * K;
        }
        __syncthreads();

        #pragma unroll 8
        for (int dd = 0; dd < DT; ++dd) {
            const float wv = ws[d0 + dd];
            float hi[2], hj[2];
            hi[0] = hjs[(i0 + ti    ) * PSTR + dd];   // wave-uniform broadcast
            hi[1] = hjs[(i0 + ti + 2) * PSTR + dd];
            hj[0] = hjs[(tj        ) * PSTR + dd];    // lane stride 17 -> conflict-free
            hj[1] = hjs[(tj + 256  ) * PSTR + dd];
            #pragma unroll
            for (int ii = 0; ii < 2; ++ii) {
                #pragma unroll
                for (int jj = 0; jj < 2; ++jj) {
                    float a = hi[ii] + hj[jj];                  // K*(Hi+Hj)
                    float e = __builtin_amdgcn_exp2f(a);        // e^{2(Hi+Hj)}
                    float r = __builtin_amdgcn_rcpf(e + 1.0f);  // sigmoid(-2x)
                    acc[ii][jj] = fmaf(wv, r, acc[ii][jj]);
                }
            }
        }
    }

    // ---- scores (shifted by row constant) to LDS ----
    __syncthreads();
    #pragma unroll
    for (int ii = 0; ii < 2; ++ii)
        #pragma unroll
        for (int jj = 0; jj < 2; ++jj)
            sc[(ti + 2 * ii) * L_ + tj + 256 * jj] = -2.0f * acc[ii][jj];
    __syncthreads();

    // ---- softmax: one wave per row (waves 0..3; waves 4..7 idle -> other block runs) ----
    if (tid < TI * 64) {
        const int row  = tid >> 6;    // 0..3
        const int lane = tid & 63;
        float v[8];
        float m = -1e30f;
        #pragma unroll
        for (int k = 0; k < 8; ++k) {
            v[k] = sc[row * L_ + lane + 64 * k];
            m = fmaxf(m, v[k]);
        }
        #pragma unroll
        for (int off = 1; off < 64; off <<= 1)
            m = fmaxf(m, __shfl_xor(m, off, 64));
        const float L2E = 1.4426950408889634f;
        float s = 0.0f;
        #pragma unroll
        for (int k = 0; k < 8; ++k) {
            v[k] = __builtin_amdgcn_exp2f((v[k] - m) * L2E);
            s += v[k];
        }
        #pragma unroll
        for (int off = 1; off < 64; off <<= 1)
            s += __shfl_xor(s, off, 64);
        const float inv = __builtin_amdgcn_rcpf(s);
        float* aRow = aOut + ((size_t)(b * L_ + i0 + row)) * L_;
        #pragma unroll
        for (int k = 0; k < 8; ++k) {
            float a = v[k] * inv;
            sc[row * L_ + lane + 64 * k] = a;   // keep alpha in LDS for r-phase
            aRow[lane + 64 * k] = a;
        }
    }
    __syncthreads();

    // ---- r[i,:] = sum_j alpha[i,j] * H[b,j,:]  (float2 over d, 128 thr/row) ----
    {
        const int i  = tid >> 7;     // 0..3
        const int d2 = tid & 127;    // float2 index, 128 per row
        const float2* Hb2 = (const float2*)Hb;   // [512][128]
        float2 racc = {0.0f, 0.0f};
        #pragma unroll 8
        for (int j = 0; j < L_; ++j) {
            float a  = sc[i * L_ + j];           // wave-uniform broadcast
            float2 h = Hb2[(size_t)j * (D_ / 2) + d2];
            racc.x = fmaf(a, h.x, racc.x);
            racc.y = fmaf(a, h.y, racc.y);
        }
        float2* R2 = (float2*)rOut;
        R2[((size_t)(b * L_ + i0 + i)) * (D_ / 2) + d2] = racc;
    }
}

extern "C" void kernel_launch(void* const* d_in, const int* in_sizes, int n_in,
                              void* d_out, int out_size, void* d_ws, size_t ws_size,
                              hipStream_t stream) {
    const float* H = (const float*)d_in[0];
    const float* w = (const float*)d_in[1];
    // d_in[2] (bias) unused: softmax shift-invariance cancels it.
    float* rOut = (float*)d_out;
    float* aOut = rOut + (size_t)B_ * L_ * D_;
    dim3 grid(B_ * (L_ / TI));   // 512 blocks -> 2 blocks/CU
    tanh_attn_kernel<<<grid, NTHREADS, 0, stream>>>(H, w, rOut, aOut);
}

// Round 3
// 151.182 us; speedup vs baseline: 1.1633x; 1.1633x over previous
//
#include <hip/hip_runtime.h>

// TanhAttention: B=4, L=512, D=256
//   scores[b,i,j] = sum_d tanh(H[b,i,d]+H[b,j,d]) * w[d] + bias
//   alpha = softmax_j(scores); r = alpha @ H
// Outputs concatenated: r (524288 floats) then alpha (1048576 floats).
//
// Math: sum_d w*tanh = (sum_d w) - 2*sum_d w*sigmoid, sigmoid = 1/(1+exp2(K*(hi+hj))),
//       K = 2*log2(e) folded into the staged (LDS) copies of H.
//       Softmax shift-invariance cancels the row constant (sum w + bias) -> bias unused.
//
// R2 structure (per-CU issue-cycle bound; delete issue cycles):
//  - grid 256, TI=8, 512 thr (R1's 2-blocks/CU duplicated staging and regressed)
//  - hjs[dd][j] transposed layout: lane-consecutive j -> conflict-free; j-pair ds_read_b64
//  - hi is wave-uniform: tiny his[8][DT] buffer -> registers once per tile (b128 broadcast)
//  - float2 math -> v_pk_add/pk_fma_f32 candidates
//  - double-buffered staging, loads for t+1 issued before compute(t), 1 barrier/tile

#define B_ 4
#define L_ 512
#define D_ 256
#define TI 8
#define DT 8
#define NT (D_ / DT)      // 32 d-tiles
#define NTHREADS 512

typedef float v2f __attribute__((ext_vector_type(2)));

__global__ __launch_bounds__(NTHREADS, 1) void tanh_attn_kernel(
    const float* __restrict__ H, const float* __restrict__ w,
    float* __restrict__ rOut, float* __restrict__ aOut)
{
    __shared__ float hjs[2][DT][L_];   // 32 KB, K-scaled H[b] d-tile, [dd][j] (transposed)
    __shared__ float his[2][TI][DT];   // 512 B, K-scaled i-rows
    __shared__ float ws[D_];           // 1 KB
    __shared__ float sc[TI][L_];       // 16 KB (scores, then alpha)
    // total 49.7 KB

    const int tid = threadIdx.x;
    const int blk = blockIdx.x;        // 0..255
    const int b   = blk >> 6;
    const int i0  = (blk & 63) * TI;
    const float K = 2.8853900817779268f;  // 2*log2(e)

    const float* Hb = H + (size_t)b * L_ * D_;

    if (tid < D_) ws[tid] = w[tid];

    const int ti  = tid >> 8;          // 0..1, wave-uniform; i = i0 + ti + 2*ii, ii=0..3
    const int tj2 = tid & 255;         // j-pair index; j = 2*tj2, 2*tj2+1

    v2f acc[4];
    #pragma unroll
    for (int ii = 0; ii < 4; ++ii) acc[ii] = (v2f){0.0f, 0.0f};

    // ---- prologue: stage tile 0 ----
    {
        float4 v0 = *(const float4*)(Hb + tid * D_ + 0);
        float4 v1 = *(const float4*)(Hb + tid * D_ + 4);
        hjs[0][0][tid] = v0.x * K; hjs[0][1][tid] = v0.y * K;
        hjs[0][2][tid] = v0.z * K; hjs[0][3][tid] = v0.w * K;
        hjs[0][4][tid] = v1.x * K; hjs[0][5][tid] = v1.y * K;
        hjs[0][6][tid] = v1.z * K; hjs[0][7][tid] = v1.w * K;
        if (tid < TI * 2) {
            const int r = tid >> 1, q = tid & 1;
            float4 hv = *(const float4*)(Hb + (i0 + r) * D_ + 4 * q);
            float* dp = &his[0][r][4 * q];
            dp[0] = hv.x * K; dp[1] = hv.y * K; dp[2] = hv.z * K; dp[3] = hv.w * K;
        }
    }
    __syncthreads();

    // ---- main pipelined loop over d-tiles ----
    for (int t = 0; t < NT; ++t) {
        const int cur = t & 1;
        // issue global loads for tile t+1 early (latency hides under compute)
        float4 n0, n1, nh;
        const bool more = (t + 1 < NT);
        if (more) {
            const int d0n = (t + 1) * DT;
            n0 = *(const float4*)(Hb + tid * D_ + d0n);
            n1 = *(const float4*)(Hb + tid * D_ + d0n + 4);
            if (tid < TI * 2) {
                const int r = tid >> 1, q = tid & 1;
                nh = *(const float4*)(Hb + (i0 + r) * D_ + d0n + 4 * q);
            }
        }

        // wave-uniform hi / w into registers (broadcast b128 reads)
        float hi[4][DT];
        float wr[DT];
        #pragma unroll
        for (int ii = 0; ii < 4; ++ii)
            #pragma unroll
            for (int dd = 0; dd < DT; ++dd)
                hi[ii][dd] = his[cur][ti + 2 * ii][dd];
        #pragma unroll
        for (int dd = 0; dd < DT; ++dd) wr[dd] = ws[t * DT + dd];

        #pragma unroll
        for (int dd = 0; dd < DT; ++dd) {
            const v2f hj = *(const v2f*)&hjs[cur][dd][2 * tj2];  // 1 b64, conflict-free
            #pragma unroll
            for (int ii = 0; ii < 4; ++ii) {
                v2f a = hj + hi[ii][dd];                  // pk_add (= K*(Hi+Hj))
                v2f e;
                e.x = __builtin_amdgcn_exp2f(a.x);
                e.y = __builtin_amdgcn_exp2f(a.y);
                v2f s = e + 1.0f;                         // pk_add
                v2f r;
                r.x = __builtin_amdgcn_rcpf(s.x);
                r.y = __builtin_amdgcn_rcpf(s.y);
                acc[ii] += wr[dd] * r;                    // pk_fma
            }
        }

        if (more) {
            const int nb = 1 - cur;
            hjs[nb][0][tid] = n0.x * K; hjs[nb][1][tid] = n0.y * K;
            hjs[nb][2][tid] = n0.z * K; hjs[nb][3][tid] = n0.w * K;
            hjs[nb][4][tid] = n1.x * K; hjs[nb][5][tid] = n1.y * K;
            hjs[nb][6][tid] = n1.z * K; hjs[nb][7][tid] = n1.w * K;
            if (tid < TI * 2) {
                const int r = tid >> 1, q = tid & 1;
                float* dp = &his[nb][r][4 * q];
                dp[0] = nh.x * K; dp[1] = nh.y * K; dp[2] = nh.z * K; dp[3] = nh.w * K;
            }
        }
        __syncthreads();
    }

    // ---- scores (shifted by row constant) to LDS ----
    #pragma unroll
    for (int ii = 0; ii < 4; ++ii) {
        v2f s2 = -2.0f * acc[ii];
        *(v2f*)&sc[ti + 2 * ii][2 * tj2] = s2;    // b64, conflict-free
    }
    __syncthreads();

    // ---- softmax: one wave per row ----
    const int row  = tid >> 6;    // 0..7
    const int lane = tid & 63;
    {
        float v[8];
        float m = -1e30f;
        #pragma unroll
        for (int k = 0; k < 8; ++k) {
            v[k] = sc[row][lane + 64 * k];
            m = fmaxf(m, v[k]);
        }
        #pragma unroll
        for (int off = 1; off < 64; off <<= 1)
            m = fmaxf(m, __shfl_xor(m, off, 64));
        const float L2E = 1.4426950408889634f;
        float s = 0.0f;
        #pragma unroll
        for (int k = 0; k < 8; ++k) {
            v[k] = __builtin_amdgcn_exp2f((v[k] - m) * L2E);
            s += v[k];
        }
        #pragma unroll
        for (int off = 1; off < 64; off <<= 1)
            s += __shfl_xor(s, off, 64);
        const float inv = __builtin_amdgcn_rcpf(s);
        float* aRow = aOut + ((size_t)(b * L_ + i0 + row)) * L_;
        #pragma unroll
        for (int k = 0; k < 8; ++k) {
            float a = v[k] * inv;
            sc[row][lane + 64 * k] = a;   // keep alpha in LDS for r-phase
            aRow[lane + 64 * k] = a;
        }
    }
    __syncthreads();

    // ---- r[i,:] = sum_j alpha[i,j] * H[b,j,:]  (float4 over d, one wave per row) ----
    {
        const int i  = row;          // 0..7
        const int d4 = lane;         // 0..63 float4 index
        const float4* Hb4 = (const float4*)Hb;   // [512][64] (raw H)
        float4 racc = {0.0f, 0.0f, 0.0f, 0.0f};
        #pragma unroll 8
        for (int j = 0; j < L_; ++j) {
            float a  = sc[i][j];                 // wave-uniform broadcast
            float4 h = Hb4[(size_t)j * (D_ / 4) + d4];
            racc.x = fmaf(a, h.x, racc.x);
            racc.y = fmaf(a, h.y, racc.y);
            racc.z = fmaf(a, h.z, racc.z);
            racc.w = fmaf(a, h.w, racc.w);
        }
        float4* R4 = (float4*)rOut;
        R4[((size_t)(b * L_ + i0 + i)) * (D_ / 4) + d4] = racc;
    }
}

extern "C" void kernel_launch(void* const* d_in, const int* in_sizes, int n_in,
                              void* d_out, int out_size, void* d_ws, size_t ws_size,
                              hipStream_t stream) {
    const float* H = (const float*)d_in[0];
    const float* w = (const float*)d_in[1];
    // d_in[2] (bias) unused: softmax shift-invariance cancels it.
    float* rOut = (float*)d_out;
    float* aOut = rOut + (size_t)B_ * L_ * D_;
    dim3 grid(B_ * (L_ / TI));   // 256 blocks, 1 per CU
    tanh_attn_kernel<<<grid, NTHREADS, 0, stream>>>(H, w, rOut, aOut);
}

// Round 4
// 128.585 us; speedup vs baseline: 1.3677x; 1.1757x over previous
//
#include <hip/hip_runtime.h>

// TanhAttention: B=4, L=512, D=256
//   scores[b,i,j] = sum_d tanh(H[b,i,d]+H[b,j,d]) * w[d] + bias
//   alpha = softmax_j(scores); r = alpha @ H
// Outputs concatenated: r (524288 floats) then alpha (1048576 floats).
//
// Math: sum_d w*tanh = (sum_d w) - 2*sum_d w*sigmoid, sigmoid = 1/(1+exp2(K*(hi+hj))),
//       K = 2*log2(e) folded into staged copies of H.
//       Softmax shift-invariance cancels the global constant (sum w + bias) -> bias unused.
//
// R3: scores are SYMMETRIC in (i,j) -> compute only upper-triangular 32x32 tiles
// (136 of 256 per batch = 53% of the trans work, the measured bottleneck), mirror
// via LDS transpose. Scores staged in the alpha region of d_out; second kernel does
// row softmax in place + r = alpha @ H. Small 4-wave blocks, 4 resident/CU,
// overlap each other's barriers (R1 showed one fat block can't hide trans latency).

#define B_ 4
#define L_ 512
#define D_ 256
#define TS 32          // tile side
#define NTILE 16       // L_/TS
#define NTRI 136       // NTILE*(NTILE+1)/2
#define DT 8           // d-tile
#define NDT (D_ / DT)  // 32
#define LSTR 36        // padded LDS row stride (16B-aligned quads, conflict-free)

typedef float v4f __attribute__((ext_vector_type(4)));

__global__ __launch_bounds__(256, 4) void score_kernel(
    const float* __restrict__ H, const float* __restrict__ w,
    float* __restrict__ sOut)
{
    __shared__ float his[2][DT][LSTR];   // K-scaled i-rows, [dd][row]
    __shared__ float hjs[2][DT][LSTR];   // K-scaled j-rows, [dd][row]
    __shared__ float ws[D_];
    __shared__ float ts[TS][LSTR];       // tile transpose buffer for mirror write

    const int tid = threadIdx.x;
    const int blk = blockIdx.x;          // 0..543
    const int b   = blk / NTRI;
    int t = blk - b * NTRI;
    int ti = 0;
    while (t >= NTILE - ti) { t -= NTILE - ti; ++ti; }   // uniform, <=16 iters
    const int tj = ti + t;
    const int i0 = ti * TS, j0 = tj * TS;
    const float K = 2.8853900817779268f;  // 2*log2(e)
    const float* Hb = H + (size_t)b * L_ * D_;

    ws[tid] = w[tid];

    // staging assignment (tid<128): wave0 -> i-set rows, wave1 -> j-set rows
    const int sr   = tid >> 1, sq = tid & 1;
    const int rl   = (sr < TS) ? sr : sr - TS;
    const int srow = (sr < TS) ? (i0 + sr) : (j0 + sr - TS);

    if (tid < 128) {
        float4 hv = *(const float4*)(Hb + srow * D_ + 4 * sq);
        float* dst = (sr < TS) ? &his[0][0][0] : &hjs[0][0][0];
        dst[(4 * sq + 0) * LSTR + rl] = hv.x * K;
        dst[(4 * sq + 1) * LSTR + rl] = hv.y * K;
        dst[(4 * sq + 2) * LSTR + rl] = hv.z * K;
        dst[(4 * sq + 3) * LSTR + rl] = hv.w * K;
    }
    __syncthreads();

    const int mi = tid >> 3;   // 0..31  i within tile
    const int mq = tid & 7;    // j-quad; j = 4*mq + 0..3

    v4f acc = (v4f){0.f, 0.f, 0.f, 0.f};

    for (int dt = 0; dt < NDT; ++dt) {
        const int cur  = dt & 1;
        const bool more = (dt + 1 < NDT);
        float4 nv;
        if (more && tid < 128)
            nv = *(const float4*)(Hb + srow * D_ + (dt + 1) * DT + 4 * sq);

        float hi[DT], wr[DT];
        #pragma unroll
        for (int dd = 0; dd < DT; ++dd) {
            hi[dd] = his[cur][dd][mi];        // 8 distinct addrs/wave, broadcast
            wr[dd] = ws[dt * DT + dd];        // uniform broadcast
        }
        #pragma unroll
        for (int dd = 0; dd < DT; ++dd) {
            v4f hj = *(const v4f*)&hjs[cur][dd][4 * mq];   // b128, conflict-free
            v4f a = hj + hi[dd];                            // K*(Hi+Hj)
            v4f e;
            e.x = __builtin_amdgcn_exp2f(a.x);
            e.y = __builtin_amdgcn_exp2f(a.y);
            e.z = __builtin_amdgcn_exp2f(a.z);
            e.w = __builtin_amdgcn_exp2f(a.w);
            v4f s = e + 1.0f;
            v4f r;
            r.x = __builtin_amdgcn_rcpf(s.x);
            r.y = __builtin_amdgcn_rcpf(s.y);
            r.z = __builtin_amdgcn_rcpf(s.z);
            r.w = __builtin_amdgcn_rcpf(s.w);
            acc += wr[dd] * r;
        }
        if (more && tid < 128) {
            const int nb = 1 - cur;
            float* dst = (sr < TS) ? &his[nb][0][0] : &hjs[nb][0][0];
            dst[(4 * sq + 0) * LSTR + rl] = nv.x * K;
            dst[(4 * sq + 1) * LSTR + rl] = nv.y * K;
            dst[(4 * sq + 2) * LSTR + rl] = nv.z * K;
            dst[(4 * sq + 3) * LSTR + rl] = nv.w * K;
        }
        __syncthreads();
    }

    // shifted score quad (row constant cancels in softmax)
    v4f sv = -2.0f * acc;

    // upper write: coalesced b128
    *(v4f*)&sOut[((size_t)b * L_ + i0 + mi) * L_ + j0 + 4 * mq] = sv;

    // mirror write via LDS transpose (off-diagonal tiles only; block-uniform branch)
    if (ti != tj) {
        *(v4f*)&ts[mi][4 * mq] = sv;
        __syncthreads();
        const int jr = tid >> 3, c4 = tid & 7;
        v4f mv;
        mv.x = ts[4 * c4 + 0][jr];
        mv.y = ts[4 * c4 + 1][jr];
        mv.z = ts[4 * c4 + 2][jr];
        mv.w = ts[4 * c4 + 3][jr];
        *(v4f*)&sOut[((size_t)b * L_ + j0 + jr) * L_ + i0 + 4 * c4] = mv;
    }
}

#define TI2 4   // rows per phase-2 block

__global__ __launch_bounds__(256, 4) void softmax_r_kernel(
    const float* __restrict__ H, float* __restrict__ rOut, float* __restrict__ aOut)
{
    __shared__ float sc[TI2][L_];   // alpha rows for the r-phase, 8 KB

    const int tid = threadIdx.x;
    const int blk = blockIdx.x;      // 0..511
    const int b   = blk >> 7;
    const int i0  = (blk & 127) * TI2;
    const int row = tid >> 6;        // 0..3 (one wave per row)
    const int lane = tid & 63;
    const float* Hb = H + (size_t)b * L_ * D_;
    float* aRow = aOut + ((size_t)b * L_ + i0 + row) * L_;

    float v[8];
    float m = -1e30f;
    #pragma unroll
    for (int k = 0; k < 8; ++k) {
        v[k] = aRow[lane + 64 * k];      // coalesced score reads (L2-hot)
        m = fmaxf(m, v[k]);
    }
    #pragma unroll
    for (int off = 1; off < 64; off <<= 1)
        m = fmaxf(m, __shfl_xor(m, off, 64));
    const float L2E = 1.4426950408889634f;
    float s = 0.0f;
    #pragma unroll
    for (int k = 0; k < 8; ++k) {
        v[k] = __builtin_amdgcn_exp2f((v[k] - m) * L2E);
        s += v[k];
    }
    #pragma unroll
    for (int off = 1; off < 64; off <<= 1)
        s += __shfl_xor(s, off, 64);
    const float inv = __builtin_amdgcn_rcpf(s);
    #pragma unroll
    for (int k = 0; k < 8; ++k) {
        float a = v[k] * inv;
        sc[row][lane + 64 * k] = a;      // keep alpha in LDS for r-phase
        aRow[lane + 64 * k] = a;         // overwrite scores in place with alpha
    }
    __syncthreads();

    // r[i,:] = sum_j alpha[i,j] * H[b,j,:]  (float4 over d, one wave per row)
    {
        const int i  = row;
        const int d4 = lane;                     // float4 index 0..63
        const float4* Hb4 = (const float4*)Hb;   // [512][64]
        float4 racc = {0.0f, 0.0f, 0.0f, 0.0f};
        #pragma unroll 8
        for (int j = 0; j < L_; ++j) {
            float a  = sc[i][j];                 // wave-uniform broadcast
            float4 h = Hb4[(size_t)j * (D_ / 4) + d4];
            racc.x = fmaf(a, h.x, racc.x);
            racc.y = fmaf(a, h.y, racc.y);
            racc.z = fmaf(a, h.z, racc.z);
            racc.w = fmaf(a, h.w, racc.w);
        }
        float4* R4 = (float4*)rOut;
        R4[((size_t)(b * L_ + i0 + i)) * (D_ / 4) + d4] = racc;
    }
}

extern "C" void kernel_launch(void* const* d_in, const int* in_sizes, int n_in,
                              void* d_out, int out_size, void* d_ws, size_t ws_size,
                              hipStream_t stream) {
    const float* H = (const float*)d_in[0];
    const float* w = (const float*)d_in[1];
    // d_in[2] (bias) unused: softmax shift-invariance cancels it.
    float* rOut = (float*)d_out;
    float* aOut = rOut + (size_t)B_ * L_ * D_;   // alpha region doubles as score scratch

    score_kernel<<<dim3(B_ * NTRI), 256, 0, stream>>>(H, w, aOut);
    softmax_r_kernel<<<dim3(B_ * (L_ / TI2)), 256, 0, stream>>>(H, rOut, aOut);
}

// Round 5
// 103.719 us; speedup vs baseline: 1.6956x; 1.2397x over previous
//
#include <hip/hip_runtime.h>

// TanhAttention: B=4, L=512, D=256
//   scores[b,i,j] = sum_d tanh(H[b,i,d]+H[b,j,d]) * w[d] + bias
//   alpha = softmax_j(scores); r = alpha @ H
// Outputs concatenated: r (524288 floats) then alpha (1048576 floats).
//
// Math: sum_d w*tanh = (sum w) - 2*sum_d w*sigmoid, sigmoid = 1/(1+exp2(K*(hi+hj))),
//       K = 2*log2(e) folded into staged copies; softmax shift-invariance cancels
//       the constant (sum w + bias) -> bias unused. Scores symmetric -> upper tiles only.
//
// R4: (a) score kernel on 32x16 half-tiles -> 1088 blocks (4.25/CU; R3's 544 = 2.1/CU
//     was the occupancy cap behind VALUBusy 43%), DT=16 (half the barriers, prefetch
//     fully hidden). (b) softmax_r: wave-cooperative j-split so H[b] is read ONCE per
//     block (L2 traffic 1 GB -> 128 MB; old version was ~40 us, the hidden half of
//     the bench time), + LDS cross-wave reduction.

#define B_ 4
#define L_ 512
#define D_ 256
#define TSI 32          // tile rows (i)
#define TSJ 16          // tile cols (j) per block (half-tile)
#define NTILE 16        // L_/32
#define NTRI 136        // upper-triangular 32x32 tiles per batch
#define DT 16           // d-tile
#define NDT (D_ / DT)   // 16
#define LSTR 36         // LDS row stride (conflict-free for the transposed staging)

typedef float v2f __attribute__((ext_vector_type(2)));
typedef float v4f __attribute__((ext_vector_type(4)));

__global__ __launch_bounds__(256, 4) void score_kernel(
    const float* __restrict__ H, const float* __restrict__ w,
    float* __restrict__ sOut)
{
    __shared__ float his[2][DT][LSTR];   // K-scaled i-rows, [dd][row], 4.6 KB
    __shared__ float hjs[2][DT][LSTR];   // K-scaled j-rows, [dd][row], 4.6 KB
    __shared__ float ws[D_];             // 1 KB
    __shared__ float ts[TSI][TSJ + 2];   // transpose buffer for mirror, 2.3 KB

    const int tid = threadIdx.x;
    const int blk = blockIdx.x;              // 0 .. 4*272-1
    const int b   = blk / (NTRI * 2);
    int t2 = blk - b * (NTRI * 2);
    const int half = t2 & 1;
    int t = t2 >> 1;
    int ti = 0;
    while (t >= NTILE - ti) { t -= NTILE - ti; ++ti; }   // uniform, <=16 iters
    const int tj = ti + t;
    const int i0 = ti * TSI;
    const int j0 = tj * TSI + half * TSJ;
    const float K = 2.8853900817779268f;  // 2*log2(e)
    const float* Hb = H + (size_t)b * L_ * D_;

    ws[tid] = w[tid];

    // staging: 48 rows (32 i + 16 j) x 16 d = 192 float4; tid<192 loads one
    const int sr = tid >> 2, sq = tid & 3;
    const bool stg = (tid < 192);
    const bool isI = (sr < TSI);
    const int rl   = isI ? sr : (sr - TSI);
    const int srow = isI ? (i0 + sr) : (j0 + sr - TSI);

    if (stg) {
        float4 hv = *(const float4*)(Hb + srow * D_ + 4 * sq);
        float* dst = isI ? &his[0][0][0] : &hjs[0][0][0];
        dst[(4 * sq + 0) * LSTR + rl] = hv.x * K;
        dst[(4 * sq + 1) * LSTR + rl] = hv.y * K;
        dst[(4 * sq + 2) * LSTR + rl] = hv.z * K;
        dst[(4 * sq + 3) * LSTR + rl] = hv.w * K;
    }
    __syncthreads();

    const int mi  = tid >> 3;   // 0..31  i within tile
    const int mj2 = tid & 7;    // j-pair; j = j0 + 2*mj2 + {0,1}

    v2f acc = (v2f){0.f, 0.f};

    for (int dt = 0; dt < NDT; ++dt) {
        const int cur   = dt & 1;
        const bool more = (dt + 1 < NDT);
        float4 nv;
        if (more && stg)
            nv = *(const float4*)(Hb + srow * D_ + (dt + 1) * DT + 4 * sq);

        float hi[DT], wr[DT];
        #pragma unroll
        for (int dd = 0; dd < DT; ++dd) {
            hi[dd] = his[cur][dd][mi];     // 8 distinct addrs/wave, broadcast, free
            wr[dd] = ws[dt * DT + dd];     // uniform broadcast
        }
        #pragma unroll
        for (int dd = 0; dd < DT; ++dd) {
            v2f hj = *(const v2f*)&hjs[cur][dd][2 * mj2];   // b64, broadcast groups
            v2f a = hj + hi[dd];                            // K*(Hi+Hj)
            v2f e;
            e.x = __builtin_amdgcn_exp2f(a.x);
            e.y = __builtin_amdgcn_exp2f(a.y);
            v2f s = e + 1.0f;
            v2f r;
            r.x = __builtin_amdgcn_rcpf(s.x);
            r.y = __builtin_amdgcn_rcpf(s.y);
            acc += wr[dd] * r;
        }
        if (more && stg) {
            const int nb = 1 - cur;
            float* dst = isI ? &his[nb][0][0] : &hjs[nb][0][0];
            dst[(4 * sq + 0) * LSTR + rl] = nv.x * K;
            dst[(4 * sq + 1) * LSTR + rl] = nv.y * K;
            dst[(4 * sq + 2) * LSTR + rl] = nv.z * K;
            dst[(4 * sq + 3) * LSTR + rl] = nv.w * K;
        }
        __syncthreads();
    }

    // shifted score pair (row constant cancels in softmax)
    v2f sv = -2.0f * acc;

    // upper write (coalesced b64 segments)
    *(v2f*)&sOut[((size_t)b * L_ + i0 + mi) * L_ + j0 + 2 * mj2] = sv;

    // mirror write via LDS transpose (off-diagonal tiles; block-uniform branch)
    if (ti != tj) {
        *(v2f*)&ts[mi][2 * mj2] = sv;
        __syncthreads();
        const int jr = tid >> 4;      // 0..15 (row of mirror chunk)
        const int c2 = tid & 15;      // i-pair
        v2f mv;
        mv.x = ts[2 * c2 + 0][jr];
        mv.y = ts[2 * c2 + 1][jr];
        *(v2f*)&sOut[((size_t)b * L_ + j0 + jr) * L_ + i0 + 2 * c2] = mv;
    }
}

// Phase 2: 256 blocks x 256 thr; 8 rows/block. Softmax in place, then
// r-phase: wave w owns j in [128w,128w+128) and accumulates partial r for
// all 8 rows -> H[b] read exactly once per block; LDS reduce across waves.
__global__ __launch_bounds__(256) void softmax_r_kernel(
    const float* __restrict__ H, float* __restrict__ rOut, float* __restrict__ aOut)
{
    __shared__ float sc[8][L_];      // alpha rows, 16 KB
    __shared__ float pr[4][8][D_];   // per-wave partial r, 32 KB

    const int tid  = threadIdx.x;
    const int blk  = blockIdx.x;     // 0..255
    const int b    = blk >> 6;
    const int i0   = (blk & 63) * 8;
    const int wv   = tid >> 6;       // wave 0..3
    const int lane = tid & 63;
    const float* Hb = H + (size_t)b * L_ * D_;
    const float L2E = 1.4426950408889634f;

    // ---- softmax: wave wv handles rows 2wv, 2wv+1 ----
    #pragma unroll
    for (int rr = 0; rr < 2; ++rr) {
        const int row = 2 * wv + rr;
        float* aRow = aOut + ((size_t)b * L_ + i0 + row) * L_;
        float v[8];
        float m = -1e30f;
        #pragma unroll
        for (int k = 0; k < 8; ++k) {
            v[k] = aRow[lane + 64 * k];      // coalesced score reads (L2-hot)
            m = fmaxf(m, v[k]);
        }
        #pragma unroll
        for (int off = 1; off < 64; off <<= 1)
            m = fmaxf(m, __shfl_xor(m, off, 64));
        float s = 0.0f;
        #pragma unroll
        for (int k = 0; k < 8; ++k) {
            v[k] = __builtin_amdgcn_exp2f((v[k] - m) * L2E);
            s += v[k];
        }
        #pragma unroll
        for (int off = 1; off < 64; off <<= 1)
            s += __shfl_xor(s, off, 64);
        const float inv = __builtin_amdgcn_rcpf(s);
        #pragma unroll
        for (int k = 0; k < 8; ++k) {
            float a = v[k] * inv;
            sc[row][lane + 64 * k] = a;
            aRow[lane + 64 * k] = a;         // overwrite scores with alpha in place
        }
    }
    __syncthreads();

    // ---- r-phase: wave-cooperative over j ----
    const int jbase = 128 * wv;
    v4f racc[8];
    #pragma unroll
    for (int r = 0; r < 8; ++r) racc[r] = (v4f){0.f, 0.f, 0.f, 0.f};
    const v4f* Hb4 = (const v4f*)Hb;         // [512][64]

    for (int js = 0; js < 128; js += 4) {
        v4f av[8];
        #pragma unroll
        for (int r = 0; r < 8; ++r)
            av[r] = *(const v4f*)&sc[r][jbase + js];   // b128 uniform broadcast
        #pragma unroll
        for (int q = 0; q < 4; ++q) {
            v4f h = Hb4[(size_t)(jbase + js + q) * (D_ / 4) + lane];
            #pragma unroll
            for (int r = 0; r < 8; ++r)
                racc[r] += av[r][q] * h;
        }
    }
    #pragma unroll
    for (int r = 0; r < 8; ++r)
        *(v4f*)&pr[wv][r][4 * lane] = racc[r];
    __syncthreads();

    // ---- reduce 4 wave-partials, write r ----
    const int fq = tid & 63;        // float4 index in D
    const int r0 = tid >> 6;        // 0..3
    #pragma unroll
    for (int rr = 0; rr < 2; ++rr) {
        const int row = r0 + 4 * rr;
        v4f s = *(const v4f*)&pr[0][row][4 * fq];
        s += *(const v4f*)&pr[1][row][4 * fq];
        s += *(const v4f*)&pr[2][row][4 * fq];
        s += *(const v4f*)&pr[3][row][4 * fq];
        *(v4f*)&rOut[((size_t)b * L_ + i0 + row) * D_ + 4 * fq] = s;
    }
}

extern "C" void kernel_launch(void* const* d_in, const int* in_sizes, int n_in,
                              void* d_out, int out_size, void* d_ws, size_t ws_size,
                              hipStream_t stream) {
    const float* H = (const float*)d_in[0];
    const float* w = (const float*)d_in[1];
    // d_in[2] (bias) unused: softmax shift-invariance cancels it.
    float* rOut = (float*)d_out;
    float* aOut = rOut + (size_t)B_ * L_ * D_;   // alpha region doubles as score scratch

    score_kernel<<<dim3(B_ * NTRI * 2), 256, 0, stream>>>(H, w, aOut);
    softmax_r_kernel<<<dim3(B_ * (L_ / 8)), 256, 0, stream>>>(H, rOut, aOut);
}